// Round 3
// baseline (23173.729 us; speedup 1.0000x reference)
//
#include <hip/hip_runtime.h>

// FPS: 2 batches x 131072 pts, 4096 samples/batch, seed = point 0.
// Persistent kernel, register-resident coords+dists. Per step:
//   fused dist-update + thread argmax -> DPP tournament reduce (u64 key)
//   to lane63 + readlane broadcast -> LDS 4-way block reduce (ONE barrier)
//   -> wave0 lanes 0..1 store a 32B slot {key | coords} as two
//   self-validating 16B quads (dual-scope, unacked) -> ALL waves poll:
//   lane L<32 loads quad0 of slot L, lane L>=32 loads quad1 of slot L-32
//   -> 5-level DPP reduce over lanes 0..31 -> winner coords via readlane.
// Key = dist_bits<<32 | step<<17 | (0x1FFFF - idx): u64 max ==
// (dist desc, idx asc) == jnp.argmax first-index tiebreak. Exact fp32.
//
// Round-2 evidence: FETCH 71.6->15GB (XCD-local polling works) but dur
// only -4% => poll scope wasn't the critical path; the per-step fixed
// work (2x 6-level u64 shfl_xor butterflies ~= 700cy) and the every-4th
// sc1 poll escalation were. This round: DPP reductions (~80cy each),
// poll escalation 1/32, no sleep on first 2 poll iters.
//
// Sync (placement-AGNOSTIC): dual-scope store (sc0 then sc0 sc1, same
// payload, any completion order safe, no ack wait) + escalating poll
// (sc0 L2 loads; sc0 sc1 coherence-point load every 32nd iter). Same-XCD
// pollers (the round-robin bet: batch = blockIdx%8, 32 blocks == 1 XCD)
// resolve via L2; cross-XCD placement still terminates via deep polls.
//
// Ring safety (RING=4): a block stores step s+1 only after ALL its waves
// passed the step-s poll (the one barrier gates the storer on every
// sibling wave); a block storing s+4 (first slot reuse) must have passed
// polls s+1..s+3, which require every block's store of s+3, which
// requires those blocks passed poll s+2 and hence finished polling s.
// Argument uses poll passes only, not store acks. Zeroed slots never
// tag-match (s in 1..4095).

#define NB    32      // blocks per batch
#define TPB   256     // 4 waves
#define PPT   16      // 32*256*16 = 131072
#define NPB   131072
#define MSAMP 4096
#define RING  4

typedef unsigned long long u64;
typedef unsigned int u32;
typedef __attribute__((ext_vector_type(4))) u32 u32x4;

// L2-scope poll load (bypass L1, hit XCD-shared L2)
__device__ __forceinline__ u32x4 ld16_l2(const u32* p) {
  u32x4 r;
  asm volatile("global_load_dwordx4 %0, %1, off sc0\n\t"
               "s_waitcnt vmcnt(0)" : "=v"(r) : "v"(p) : "memory");
  return r;
}
// device-scope poll load (coherence point)
__device__ __forceinline__ u32x4 ld16_sys(const u32* p) {
  u32x4 r;
  asm volatile("global_load_dwordx4 %0, %1, off sc0 sc1\n\t"
               "s_waitcnt vmcnt(0)" : "=v"(r) : "v"(p) : "memory");
  return r;
}
// dual-scope store, no ack wait (ack drains under the first poll load)
__device__ __forceinline__ void st16_dual(u32* p, u32x4 v) {
  asm volatile("global_store_dwordx4 %0, %1, off sc0\n\t"
               "global_store_dwordx4 %0, %1, off sc0 sc1"
               :: "v"(p), "v"(v) : "memory");
}

// ---- DPP helpers: u64 move with a compile-time DPP control ----------
template<int CTRL>
__device__ __forceinline__ u64 dpp_move64(u64 x) {
  int lo = (int)(u32)(x & 0xFFFFFFFFull);
  int hi = (int)(u32)(x >> 32);
  // bound_ctrl=false: lanes with invalid DPP source keep OLD (own) value,
  // so the subsequent max-compare is a no-op for them.
  int nlo = __builtin_amdgcn_update_dpp(lo, lo, CTRL, 0xF, 0xF, false);
  int nhi = __builtin_amdgcn_update_dpp(hi, hi, CTRL, 0xF, 0xF, false);
  return ((u64)(u32)nhi << 32) | (u64)(u32)nlo;
}
#define DPP_ROW_SHR(n)  (0x110 + (n))
#define DPP_BCAST15     0x142
#define DPP_BCAST31     0x143

// tournament max of u64 keys -> full-wave max lands in lane 63
__device__ __forceinline__ u64 dpp_max64_to63(u64 k) {
  u64 t;
  t = dpp_move64<DPP_ROW_SHR(1)>(k); if (t > k) k = t;
  t = dpp_move64<DPP_ROW_SHR(2)>(k); if (t > k) k = t;
  t = dpp_move64<DPP_ROW_SHR(4)>(k); if (t > k) k = t;
  t = dpp_move64<DPP_ROW_SHR(8)>(k); if (t > k) k = t;  // lane15 of each row
  t = dpp_move64<DPP_BCAST15>(k);    if (t > k) k = t;  // lane31/63 halves
  t = dpp_move64<DPP_BCAST31>(k);    if (t > k) k = t;  // lane63 = global
  return k;
}
// max over lanes 0..31 lands in lane 31 (rows 0,1 only matter)
__device__ __forceinline__ u64 dpp_max64_to31(u64 k) {
  u64 t;
  t = dpp_move64<DPP_ROW_SHR(1)>(k); if (t > k) k = t;
  t = dpp_move64<DPP_ROW_SHR(2)>(k); if (t > k) k = t;
  t = dpp_move64<DPP_ROW_SHR(4)>(k); if (t > k) k = t;
  t = dpp_move64<DPP_ROW_SHR(8)>(k); if (t > k) k = t;  // lane15, lane31
  t = dpp_move64<DPP_BCAST15>(k);    if (t > k) k = t;  // lane31 = max(0..31)
  return k;
}

__device__ __forceinline__ u64 bcast_key(u64 k, int srclane) {
  u32 lo = (u32)__builtin_amdgcn_readlane((int)(u32)(k & 0xFFFFFFFFull), srclane);
  u32 hi = (u32)__builtin_amdgcn_readlane((int)(u32)(k >> 32), srclane);
  return ((u64)hi << 32) | (u64)lo;
}
__device__ __forceinline__ float bcast_f32(float v, int srclane) {
  return __uint_as_float((u32)__builtin_amdgcn_readlane((int)__float_as_uint(v), srclane));
}

__global__ __launch_bounds__(TPB, 1)
void fps_kernel(const float4* __restrict__ pts, float* __restrict__ out,
                u32* __restrict__ slots)
{
#pragma clang fp contract(off)
  const int sub = blockIdx.x & 7;            // XCD id under round-robin
  if (sub >= 2) return;                      // 192 placeholder blocks exit
  const int batch = sub;
  const int blk   = blockIdx.x >> 3;         // 0..31
  const int tid   = threadIdx.x;
  const int lane  = tid & 63;
  const int wv    = tid >> 6;

  __shared__ u64   s_key[4];
  __shared__ float s_cx[4], s_cy[4], s_cz[4];

  const float4* bpts = pts + (size_t)batch * NPB;
  u32* bslots = slots + (size_t)batch * (RING * NB * 8);  // 8 u32 per slot

  const int base = blk * (TPB * PPT);

  float px[PPT], py[PPT], pz[PPT], dist[PPT];
#pragma unroll
  for (int k = 0; k < PPT; ++k) {
    float4 p = bpts[base + k * TPB + tid];   // row = (b, x, y, z)
    px[k] = p.y; py[k] = p.z; pz[k] = p.w;
    dist[k] = __builtin_inff();              // min(inf, d) == d bit-exactly
  }

  float4 seed = bpts[0];
  float sx = seed.y, sy = seed.z, sz = seed.w;
  if (blk == 0 && wv == 0 && lane == 0) {
    float4 o; o.x = (float)batch; o.y = sx; o.z = sy; o.w = sz;
    *(float4*)(out + (size_t)batch * MSAMP * 4) = o;
  }

  for (int s = 1; s < MSAMP; ++s) {
    // ---- fused dist update + per-thread argmax, coords tracked ----
    float bestd = -1.0f, bx = 0.f, by = 0.f, bz = 0.f; int besti = 0;
#pragma unroll
    for (int k = 0; k < PPT; ++k) {
      float dx = px[k] - sx, dy = py[k] - sy, dz = pz[k] - sz;
      float d2 = __fadd_rn(__fadd_rn(__fmul_rn(dx, dx), __fmul_rn(dy, dy)),
                           __fmul_rn(dz, dz));
      float nd = fminf(dist[k], d2);
      dist[k] = nd;
      if (nd > bestd) {                      // strict '>': first-index tiebreak
        bestd = nd; besti = base + k * TPB + tid;
        bx = px[k]; by = py[k]; bz = pz[k];
      }
    }

    u64 pv0 = ((u64)__float_as_uint(bestd) << 32) | ((u64)s << 17) |
              (u64)(0x1FFFF - besti);

    // ---- wave argmax: DPP tournament to lane63, readlane broadcast ----
    u64 kw = bcast_key(dpp_max64_to63(pv0), 63);
    int wl = __ffsll(__ballot(pv0 == kw)) - 1;   // unique: idx embedded
    float wx = bcast_f32(bx, wl), wy = bcast_f32(by, wl), wz = bcast_f32(bz, wl);
    if (lane == 0) { s_key[wv] = kw; s_cx[wv] = wx; s_cy[wv] = wy; s_cz[wv] = wz; }
    __syncthreads();                         // the ONE barrier per step

    u32* ring = bslots + (size_t)(s & (RING - 1)) * (NB * 8);
    if (wv == 0 && lane < 2) {
      // 4-way block reduce from LDS (redundant across lanes 0..1)
      u64 k0 = s_key[0], k1 = s_key[1], k2 = s_key[2], k3 = s_key[3];
      int bi = 0; u64 bk = k0;
      if (k1 > bk) { bk = k1; bi = 1; }
      if (k2 > bk) { bk = k2; bi = 2; }
      if (k3 > bk) { bk = k3; bi = 3; }
      u32x4 q;
      if (lane == 0) {                       // quad0: key + x,y (tag in key)
        q.x = (u32)(bk & 0xFFFFFFFFull); q.y = (u32)(bk >> 32);
        q.z = __float_as_uint(s_cx[bi]);  q.w = __float_as_uint(s_cy[bi]);
      } else {                               // quad1: tag + z
        q.x = (u32)s; q.y = __float_as_uint(s_cz[bi]); q.z = 0u; q.w = 0u;
      }
      st16_dual(ring + blk * 8 + lane * 4, q);   // dual scope, no ack wait
    }

    // ---- poll: lane L<32 -> quad0 of slot L; lane L>=32 -> quad1 of
    //      slot L-32. sc0 (L2) normally; device scope every 32nd iter
    //      (placement-agnostic escape hatch only). ----
    const u32* pp = ring + ((lane < 32) ? (lane * 8) : ((lane - 32) * 8 + 4));
    u32x4 q;
    for (u32 it = 0; ; ++it) {
      q = ((it & 31u) == 31u) ? ld16_sys(pp) : ld16_l2(pp);
      bool ok = (lane < 32) ? ((q.x >> 17) == (u32)s) : (q.x == (u32)s);
      if (__ballot(ok) == ~0ull) break;
      if (it >= 2) __builtin_amdgcn_s_sleep(1);  // backoff only when slow
    }

    // ---- cross-block argmax: 5-level DPP over lanes 0..31 ----
    u64 key = (lane < 32) ? (((u64)q.y << 32) | (u64)q.x) : 0ull;
    u64 w = bcast_key(dpp_max64_to31(key), 31);
    int wl2 = __ffsll(__ballot(key == w && lane < 32)) - 1;
    sx = bcast_f32(__uint_as_float(q.z), wl2);        // x from quad0 lane
    sy = bcast_f32(__uint_as_float(q.w), wl2);        // y from quad0 lane
    sz = bcast_f32(__uint_as_float(q.y), wl2 + 32);   // z from quad1 lane

    if (blk == 0 && wv == 0 && lane == 0) {
      float4 o; o.x = (float)batch; o.y = sx; o.z = sy; o.w = sz;
      *(float4*)(out + (size_t)(batch * MSAMP + s) * 4) = o;
    }
  }
}

extern "C" void kernel_launch(void* const* d_in, const int* in_sizes, int n_in,
                              void* d_out, int out_size, void* d_ws, size_t ws_size,
                              hipStream_t stream) {
  const float4* pts = (const float4*)d_in[0];
  float* out = (float*)d_out;
  u32* slots = (u32*)d_ws;

  // Zero both batches' slot rings (8 KB): stale tags can never validate.
  hipMemsetAsync(d_ws, 0, (size_t)2 * RING * NB * 32, stream);

  dim3 grid(256), block(TPB);
  hipLaunchKernelGGL(fps_kernel, grid, block, 0, stream, pts, out, slots);
}